// Round 18
// baseline (166.486 us; speedup 1.0000x reference)
//
#include <hip/hip_runtime.h>
#include <hip/hip_bf16.h>
#include <math.h>

typedef short bf16x8 __attribute__((ext_vector_type(8)));
typedef float f32x4 __attribute__((ext_vector_type(4)));
typedef unsigned short us8 __attribute__((ext_vector_type(8)));
typedef unsigned short us4 __attribute__((ext_vector_type(4)));

namespace {
constexpr int B_ = 128;
constexpr int S_ = 64;
constexpr int H_ = 1000;
constexpr int A_ = 1000;
constexpr int M_ = 500;
constexpr int V_ = 30000;
constexpr int E_ = 620;

constexpr int KP_OUT  = 2048;
constexpr int KP_HP   = 1024;
constexpr int KP_PRED = 512;
constexpr int LD_CAT  = 3712;  // [hidden 1000 | emb 620 | ctx 2000 | pad]
constexpr int NP_A    = 1024;
constexpr int NP_3H   = 3072;
constexpr int OROWS   = 8192;

// split-K factors (R18: doubled for latency hiding; consumers sum these)
constexpr int Z_HP = 8, Z_GI = 12, Z_GH = 8, Z_MO = 12, Z_OP = 2;

__device__ __forceinline__ unsigned short f2b(float f) {
  __hip_bfloat16 h = __float2bfloat16(f);
  return *reinterpret_cast<unsigned short*>(&h);
}
__device__ __forceinline__ float b2f(unsigned short u) {
  unsigned v = ((unsigned)u) << 16;
  return __uint_as_float(v);
}
__device__ __forceinline__ float sigmoidf_(float x) {
  return 1.0f / (1.0f + __expf(-x));
}
__device__ __forceinline__ void load_lds16(const void* g, void* l) {
  auto gp = reinterpret_cast<const __attribute__((address_space(1))) char*>(
      reinterpret_cast<uintptr_t>(g));
  unsigned loff = (unsigned)(uintptr_t)l;
  auto lp = reinterpret_cast<__attribute__((address_space(3))) char*>(loff);
  __builtin_amdgcn_global_load_lds(gp, lp, 16, 0, 0);
}
}  // namespace

// ---------------------------------------------------------------------------
// Merged cast v4 (unroll-4). R17 version.
// ---------------------------------------------------------------------------
struct CJob {
  const float* src; unsigned short* dst;
  int nchunks, cpr, Kel, Rs, ld, coff, Wlim, bstart, nblk;
};

__global__ __launch_bounds__(256) void megacast(CJob j0, CJob j1, CJob j2)
{
  const int bid = blockIdx.x;
  CJob j = j0;
  if (bid >= j1.bstart) j = j1;
  if (bid >= j2.bstart) j = j2;

  const int tpj = j.nblk << 8;
  const int base = ((bid - j.bstart) << 8) + (int)threadIdx.x;

  for (int i = base; i < j.nchunks; i += tpj * 4) {
    int rr[4], cc[4];
    bool ok[4], fast[4];
    float4 lo[4], hi[4];
#pragma unroll
    for (int u = 0; u < 4; ++u) {
      const int idx = i + u * tpj;
      ok[u] = idx < j.nchunks;
      const int r = ok[u] ? (idx / j.cpr) : 0;
      const int c = ok[u] ? ((idx - r * j.cpr) << 3) : 0;
      rr[u] = r; cc[u] = c;
      fast[u] = ok[u] && (r < j.Rs) && (c + 8 <= j.Kel);
      if (fast[u]) {
        const float* s = j.src + (size_t)r * j.Kel + c;
        lo[u] = *(const float4*)s;
        hi[u] = *(const float4*)(s + 4);
      }
    }
#pragma unroll
    for (int u = 0; u < 4; ++u) {
      if (!ok[u]) continue;
      unsigned short* drow = j.dst + (size_t)rr[u] * j.ld + j.coff;
      if (fast[u]) {
        us8 o;
        o[0] = f2b(lo[u].x); o[1] = f2b(lo[u].y);
        o[2] = f2b(lo[u].z); o[3] = f2b(lo[u].w);
        o[4] = f2b(hi[u].x); o[5] = f2b(hi[u].y);
        o[6] = f2b(hi[u].z); o[7] = f2b(hi[u].w);
        *(us8*)(drow + cc[u]) = o;
      } else {
#pragma unroll
        for (int e = 0; e < 8; ++e) {
          const int c = cc[u] + e;
          if (c < j.Wlim) {
            const float v = (rr[u] < j.Rs && c < j.Kel)
                                ? j.src[(size_t)rr[u] * j.Kel + c] : 0.f;
            drow[c] = f2b(v);
          }
        }
      }
    }
  }
}

// ---------------------------------------------------------------------------
// Skinny GEMM v2: fp32-B direct, BK=64, double-buffered swizzled LDS.
// R18: Af loads issued BEFORE stage_load(k+1) so the compiler's pre-MFMA
// wait is a counted vmcnt (Af = older group; sf prefetch stays in flight
// through the MFMAs). R17 post-mortem: the old order drained the prefetch
// every step (in-order vmcnt retirement).
// ---------------------------------------------------------------------------
struct SJob {
  const unsigned short* A; int lda;
  const float* B; int ldb;
  int Nv, Kv;
  float* C; int ldc;
  const float* bias; int Ncol;
  int nK, Z, ntiles, bstart;
};

__global__ __launch_bounds__(256, 4) void gemm_skinny(
    SJob j0, SJob j1, SJob j2, SJob j3)
{
  __shared__ __align__(16) char Bs[2][4096];

  const int bid = blockIdx.x;
  SJob j = j0;
  if (bid >= j1.bstart) j = j1;
  if (bid >= j2.bstart) j = j2;
  if (bid >= j3.bstart) j = j3;
  const int lb = bid - j.bstart;
  const int tile = lb % j.ntiles, z = lb / j.ntiles;
  const int n0 = tile * 32;
  const int ks = (int)((long)j.nK * z / j.Z);
  const int ke = (int)((long)j.nK * (z + 1) / j.Z);

  const int t = threadIdx.x, lane = t & 63, wid = t >> 6;
  const int l15 = lane & 15, l4 = lane >> 4;
  const int mrow = (wid & 1) * 64;
  const int whalf = wid >> 1;

  const int srow = t >> 3;
  const int skq = (t & 7) * 8;
  const int grow = n0 + srow;
  const bool rowok = grow < j.Nv;
  const float* Bp = j.B + (size_t)(rowok ? grow : 0) * j.ldb;
  const unsigned swcol = (unsigned)(skq * 2) ^ (((unsigned)srow & 7u) << 4);

  const unsigned short* Arow = j.A + (size_t)(mrow + l15) * j.lda + l4 * 8;
  const int brow = whalf * 16 + l15;
  const unsigned bb = (unsigned)brow * 128;
  const unsigned bsw = (((unsigned)brow & 7u) << 4);

  float4 sf0, sf1;
  auto stage_load = [&](int kst) {
    const int gk = kst * 64 + skq;
    sf0 = make_float4(0.f, 0.f, 0.f, 0.f);
    sf1 = make_float4(0.f, 0.f, 0.f, 0.f);
    if (rowok) {
      if (gk + 8 <= j.Kv) {
        sf0 = *(const float4*)(Bp + gk);
        sf1 = *(const float4*)(Bp + gk + 4);
      } else {
        float tmp[8];
#pragma unroll
        for (int e = 0; e < 8; ++e)
          tmp[e] = (gk + e < j.Kv) ? Bp[gk + e] : 0.f;
        sf0 = make_float4(tmp[0], tmp[1], tmp[2], tmp[3]);
        sf1 = make_float4(tmp[4], tmp[5], tmp[6], tmp[7]);
      }
    }
  };
  auto stage_write = [&](int buf) {
    us8 o;
    o[0] = f2b(sf0.x); o[1] = f2b(sf0.y); o[2] = f2b(sf0.z); o[3] = f2b(sf0.w);
    o[4] = f2b(sf1.x); o[5] = f2b(sf1.y); o[6] = f2b(sf1.z); o[7] = f2b(sf1.w);
    *(us8*)((char*)Bs[buf] + srow * 128 + swcol) = o;
  };

  f32x4 acc[4] = {};
  stage_load(ks);
  stage_write(0);
  __syncthreads();

  for (int kst = ks; kst < ke; ++kst) {
    const int cur = (kst - ks) & 1;
    const bool more = (kst + 1 < ke);
    // Af FIRST (older VMEM group -> counted wait before MFMA)
    bf16x8 Af[4][2];
#pragma unroll
    for (int kk = 0; kk < 2; ++kk)
#pragma unroll
      for (int mf = 0; mf < 4; ++mf)
        Af[mf][kk] = *(const bf16x8*)(Arow + (size_t)mf * 16 * j.lda +
                                      kst * 64 + kk * 32);
    if (more) stage_load(kst + 1);  // sf stays in flight through MFMAs
    bf16x8 Bf[2];
#pragma unroll
    for (int kk = 0; kk < 2; ++kk)
      Bf[kk] = *(const bf16x8*)((char*)Bs[cur] + bb +
                                ((unsigned)(kk * 64 + l4 * 16) ^ bsw));
#pragma unroll
    for (int kk = 0; kk < 2; ++kk)
#pragma unroll
      for (int mf = 0; mf < 4; ++mf)
        acc[mf] = __builtin_amdgcn_mfma_f32_16x16x32_bf16(Af[mf][kk], Bf[kk],
                                                          acc[mf], 0, 0, 0);
    if (more) stage_write(cur ^ 1);
    __syncthreads();
  }

  const int c = n0 + whalf * 16 + l15;
  if (j.bias) {
    if (c < j.Ncol) {
      const float bv = j.bias[c];
#pragma unroll
      for (int mf = 0; mf < 4; ++mf) {
        const int r = mrow + mf * 16 + l4 * 4;
#pragma unroll
        for (int q = 0; q < 4; ++q)
          j.C[(size_t)(r + q) * j.ldc + c] = acc[mf][q] + bv;
      }
    }
  } else {
    float* Cz = j.C + (size_t)z * 128 * j.ldc;
#pragma unroll
    for (int mf = 0; mf < 4; ++mf) {
      const int r = mrow + mf * 16 + l4 * 4;
#pragma unroll
      for (int q = 0; q < 4; ++q)
        Cz[(size_t)(r + q) * j.ldc + c] = acc[mf][q];
    }
  }
}

// ---------------------------------------------------------------------------
// pred GEMM v4 (T3/T4 counted-vmcnt pipeline) — unchanged from R15.
// ---------------------------------------------------------------------------
__global__ __launch_bounds__(256, 2) void pred_gemm(
    const unsigned short* __restrict__ mo_bf,  // 128 x 512 bf16, K-pad zeroed
    const float* __restrict__ Wp,              // 30000 x 500 fp32
    const float* __restrict__ bias,
    float* __restrict__ C)                     // 128 x 30000
{
  __shared__ __align__(16) char Bs0[32768];  // 16 rows x 2048B fp32
  __shared__ __align__(16) char Bs1[32768];

  const int t = threadIdx.x, lane = t & 63, wid = t >> 6;
  const int l15 = lane & 15, l4 = lane >> 4;
  const int n0 = blockIdx.x * 64;
  const int mrow = wid * 32;

  bf16x8 af[2][16];
#pragma unroll
  for (int ksl = 0; ksl < 16; ++ksl)
#pragma unroll
    for (int mf = 0; mf < 2; ++mf)
      af[mf][ksl] = *(const bf16x8*)(mo_bf +
          (size_t)(mrow + mf * 16 + l15) * KP_PRED + ksl * 32 + l4 * 8);

  auto stage = [&](int st, char* buf) {
#pragma unroll
    for (int i = 0; i < 8; ++i) {
      const unsigned off = (unsigned)i * 4096 + (unsigned)t * 16;
      const unsigned row = off >> 11, colb = off & 2047u;
      const unsigned sc = colb ^ ((row & 7u) << 4);  // pre-swizzled source
      const int rg = n0 + st * 16 + (int)row;
      const bool ok = (rg < V_) && (sc + 16 <= 2000u);
      const char* src = ok ? ((const char*)Wp + (size_t)rg * 2000 + sc)
                           : (const char*)Wp;
      load_lds16(src, buf + off);
    }
  };

  f32x4 acc[4][2] = {};

  stage(0, Bs0);
  stage(1, Bs1);

#define PWAIT(N) do {                                              \
    asm volatile("s_waitcnt vmcnt(" #N ")" ::: "memory");          \
    __builtin_amdgcn_sched_barrier(0);                             \
    __builtin_amdgcn_s_barrier();                                  \
  } while (0)

#define PCOMPUTE(T, BUF) do {                                              \
    const char* Brow_ = (const char*)(BUF) + (unsigned)l15 * 2048;         \
    const unsigned sw_ = ((unsigned)l15 & 7u) << 4;                        \
    _Pragma("unroll")                                                      \
    for (int ksl = 0; ksl < 16; ++ksl) {                                   \
      const unsigned base_ = (unsigned)(ksl * 128 + l4 * 32);              \
      const float4 f0_ = *(const float4*)(Brow_ + (base_ ^ sw_));          \
      const float4 f1_ = *(const float4*)(Brow_ + ((base_ + 16) ^ sw_));   \
      bf16x8 bf_;                                                          \
      bf_[0] = (short)f2b(f0_.x); bf_[1] = (short)f2b(f0_.y);              \
      bf_[2] = (short)f2b(f0_.z); bf_[3] = (short)f2b(f0_.w);              \
      bf_[4] = (short)f2b(f1_.x); bf_[5] = (short)f2b(f1_.y);              \
      bf_[6] = (short)f2b(f1_.z); bf_[7] = (short)f2b(f1_.w);              \
      acc[T][0] = __builtin_amdgcn_mfma_f32_16x16x32_bf16(af[0][ksl], bf_, \
                                                          acc[T][0], 0, 0, 0); \
      acc[T][1] = __builtin_amdgcn_mfma_f32_16x16x32_bf16(af[1][ksl], bf_, \
                                                          acc[T][1], 0, 0, 0); \
    }                                                                      \
  } while (0)

  PWAIT(8);
  PCOMPUTE(0, Bs0);
  __builtin_amdgcn_s_barrier();
  stage(2, Bs0);

  PWAIT(8);
  PCOMPUTE(1, Bs1);
  __builtin_amdgcn_s_barrier();
  stage(3, Bs1);

  PWAIT(8);
  PCOMPUTE(2, Bs0);

  PWAIT(0);
  PCOMPUTE(3, Bs1);

#undef PWAIT
#undef PCOMPUTE

#pragma unroll
  for (int st = 0; st < 4; ++st) {
    const int c = n0 + st * 16 + l15;
    if (c < V_) {
      const float bv = bias[c];
#pragma unroll
      for (int mf = 0; mf < 2; ++mf) {
        const int r = mrow + mf * 16 + l4 * 4;
#pragma unroll
        for (int q = 0; q < 4; ++q)
          C[(size_t)(r + q) * V_ + c] = acc[st][mf][q] + bv;
      }
    }
  }
}

// ---------------------------------------------------------------------------
// o_proj GEMM (R15/R12 version): 128x128 tile, BK=64, swizzled LDS,
// global_load_lds both sides, __syncthreads, 4 blocks/CU. bf16 partials.
// ---------------------------------------------------------------------------
__global__ __launch_bounds__(256, 4) void gemm128_part(
    const unsigned short* __restrict__ Abf, int ldA,
    const unsigned short* __restrict__ Bbf, int ldB,
    unsigned short* __restrict__ Cout, int ldc, int nK)
{
  __shared__ __align__(16) char As[16384];
  __shared__ __align__(16) char Bs[16384];

  const int t = threadIdx.x;
  const int lane = t & 63, wid = t >> 6;
  const int wm = wid >> 1, wn = wid & 1;
  const int l15 = lane & 15, l4 = lane >> 4;
  const int m0 = blockIdx.x * 128;
  const int n0 = blockIdx.y * 128;
  const int z = blockIdx.z, Z = gridDim.z;
  const int ks = (int)((long)nK * z / Z), ke = (int)((long)nK * (z + 1) / Z);

  f32x4 acc[4][4] = {};

  for (int kst = ks; kst < ke; ++kst) {
    const int k0 = kst * 64;
#pragma unroll
    for (int c = 0; c < 4; ++c) {
      const unsigned ou = c * 4096 + wid * 1024;
      const unsigned oo = ou + lane * 16;
      const unsigned row = oo >> 7, cb = oo & 127u;
      const unsigned scb = cb ^ ((row & 7u) << 4);
      load_lds16((const char*)Abf + ((size_t)(m0 + row) * ldA + k0) * 2 + scb,
                 As + ou);
    }
#pragma unroll
    for (int c = 0; c < 4; ++c) {
      const unsigned ou = c * 4096 + wid * 1024;
      const unsigned oo = ou + lane * 16;
      const unsigned row = oo >> 7, cb = oo & 127u;
      const unsigned scb = cb ^ ((row & 7u) << 4);
      load_lds16((const char*)Bbf + ((size_t)(n0 + row) * ldB + k0) * 2 + scb,
                 Bs + ou);
    }
    __syncthreads();

#pragma unroll
    for (int kk = 0; kk < 2; ++kk) {
      bf16x8 af[4], bfr[4];
#pragma unroll
      for (int i = 0; i < 4; ++i) {
        const unsigned ra = wm * 64 + i * 16 + l15;
        const unsigned ca = (unsigned)(kk * 64 + l4 * 16) ^ ((ra & 7u) << 4);
        af[i] = *(const bf16x8*)(As + ra * 128 + ca);
        const unsigned rb = wn * 64 + i * 16 + l15;
        const unsigned cb2 = (unsigned)(kk * 64 + l4 * 16) ^ ((rb & 7u) << 4);
        bfr[i] = *(const bf16x8*)(Bs + rb * 128 + cb2);
      }
#pragma unroll
      for (int i = 0; i < 4; ++i)
#pragma unroll
        for (int jj = 0; jj < 4; ++jj)
          acc[i][jj] = __builtin_amdgcn_mfma_f32_16x16x32_bf16(af[i], bfr[jj],
                                                               acc[i][jj], 0, 0, 0);
    }
    __syncthreads();
  }

  unsigned short* Cz = Cout + (size_t)z * OROWS * ldc;
#pragma unroll
  for (int i = 0; i < 4; ++i) {
    const int r = m0 + wm * 64 + i * 16 + l4 * 4;
#pragma unroll
    for (int jj = 0; jj < 4; ++jj) {
      const int c = n0 + wn * 64 + jj * 16 + l15;
#pragma unroll
      for (int q = 0; q < 4; ++q)
        Cz[(size_t)(r + q) * ldc + c] = f2b(acc[i][jj][q]);
    }
  }
}

// ---------------------------------------------------------------------------
// hpc[b][c] = b_op[c] + b_hp[c] + sum_z hp_partial[z][b][c]  (Z_HP=8)
// ---------------------------------------------------------------------------
__global__ __launch_bounds__(256) void hp_combine(
    const float* __restrict__ hp, const float* __restrict__ b_op,
    const float* __restrict__ b_hp, float* __restrict__ hpc)
{
  const int idx = blockIdx.x * 256 + threadIdx.x;
  if (idx >= B_ * NP_A) return;
  const int c = idx & (NP_A - 1);
  float s = (c < A_) ? (b_op[c] + b_hp[c]) : 0.f;
#pragma unroll
  for (int zz = 0; zz < Z_HP; ++zz) s += hp[(size_t)zz * B_ * NP_A + idx];
  hpc[idx] = s;
}

// ---------------------------------------------------------------------------
// energy[r] = sum_c tanh(op0[r,c] + op1[r,c] + hpc[b,c]) * ve[c]   (opart bf16)
// ---------------------------------------------------------------------------
__global__ __launch_bounds__(256) void energy_reduce(
    const unsigned short* __restrict__ opart, const float* __restrict__ hpc,
    const float* __restrict__ ve, float* __restrict__ energy)
{
  const int r = blockIdx.x;
  const int b = r >> 6;
  const int t = threadIdx.x;
  float s = 0.f;
  if (t < 250) {
    const int c0 = t * 4;
    const us4 v0 = *(const us4*)(opart + (size_t)r * NP_A + c0);
    const us4 v1 = *(const us4*)(opart + (size_t)OROWS * NP_A + (size_t)r * NP_A + c0);
    const float4 h = *(const float4*)(hpc + (size_t)b * NP_A + c0);
    const float4 vv = *(const float4*)(ve + c0);
    s = tanhf(b2f(v0[0]) + b2f(v1[0]) + h.x) * vv.x
      + tanhf(b2f(v0[1]) + b2f(v1[1]) + h.y) * vv.y
      + tanhf(b2f(v0[2]) + b2f(v1[2]) + h.z) * vv.z
      + tanhf(b2f(v0[3]) + b2f(v1[3]) + h.w) * vv.w;
  }
#pragma unroll
  for (int w = 1; w < 64; w <<= 1) s += __shfl_xor(s, w);
  __shared__ float red[4];
  if ((t & 63) == 0) red[t >> 6] = s;
  __syncthreads();
  if (t == 0) energy[r] = red[0] + red[1] + red[2] + red[3];
}

// ---------------------------------------------------------------------------
// softmax + ctx (from outputs_bf) + cat3 build.  grid (B, 4)
// ---------------------------------------------------------------------------
__global__ __launch_bounds__(256) void softmax_ctx_cat(
    const float* __restrict__ energy, const unsigned short* __restrict__ outb,
    const float* __restrict__ hidden, const float* __restrict__ emb,
    const int* __restrict__ x, unsigned short* __restrict__ cat3)
{
  const int b = blockIdx.x, yq = blockIdx.y;
  const int t = threadIdx.x;
  __shared__ float attn[S_];
  __shared__ float sinv_s;

  if (t < 64) {
    const float e = energy[b * S_ + t];
    float m = e;
#pragma unroll
    for (int w = 1; w < 64; w <<= 1) m = fmaxf(m, __shfl_xor(m, w));
    const float p = __expf(e - m);
    float s = p;
#pragma unroll
    for (int w = 1; w < 64; w <<= 1) s += __shfl_xor(s, w);
    attn[t] = p;
    if (t == 0) sinv_s = 1.f / s;
  }
  __syncthreads();
  const float inv = sinv_s;
  unsigned short* catb = cat3 + (size_t)b * LD_CAT;

  // ctx -> cols 1620..3619
  {
    const int c0 = (250 * yq) / 4, c1 = (250 * (yq + 1)) / 4;
    const unsigned short* ob = outb + (size_t)b * S_ * KP_OUT;
    for (int kk = c0 + t; kk < c1; kk += 256) {
      float a[8] = {0.f, 0.f, 0.f, 0.f, 0.f, 0.f, 0.f, 0.f};
      for (int s = 0; s < S_; ++s) {
        const float w = attn[s];
        const us8 v = *(const us8*)(ob + (size_t)s * KP_OUT + kk * 8);
#pragma unroll
        for (int jj = 0; jj < 8; ++jj) a[jj] = fmaf(w, b2f(v[jj]), a[jj]);
      }
      us4 lo, hi;
#pragma unroll
      for (int jj = 0; jj < 4; ++jj) {
        lo[jj] = f2b(a[jj] * inv); hi[jj] = f2b(a[jj + 4] * inv);
      }
      *(us4*)(catb + 1620 + kk * 8) = lo;
      *(us4*)(catb + 1620 + kk * 8 + 4) = hi;
    }
  }
  // hidden -> cols 0..999
  {
    const int c0 = (250 * yq) / 4, c1 = (250 * (yq + 1)) / 4;
    for (int kk = c0 + t; kk < c1; kk += 256) {
      const float4 f = *(const float4*)(hidden + (size_t)b * H_ + kk * 4);
      us4 v; v[0] = f2b(f.x); v[1] = f2b(f.y); v[2] = f2b(f.z); v[3] = f2b(f.w);
      *(us4*)(catb + kk * 4) = v;
    }
  }
  // emb_x -> cols 1000..1619
  {
    const int xi = x[b];
    const int c0 = (155 * yq) / 4, c1 = (155 * (yq + 1)) / 4;
    for (int kk = c0 + t; kk < c1; kk += 256) {
      const float4 f = *(const float4*)(emb + (size_t)xi * E_ + kk * 4);
      us4 v; v[0] = f2b(f.x); v[1] = f2b(f.y); v[2] = f2b(f.z); v[3] = f2b(f.w);
      *(us4*)(catb + 1000 + kk * 4) = v;
    }
  }
  // zero pad cols 3620..3711
  if (yq == 3) {
    for (int kk = t; kk < 23; kk += 256) {
      us4 v; v[0] = 0; v[1] = 0; v[2] = 0; v[3] = 0;
      *(us4*)(catb + 3620 + kk * 4) = v;
    }
  }
}

// ---------------------------------------------------------------------------
// GRU combine: sums gi partials (Z_GI=12) + gh partials (Z_GH=8) + biases
// ---------------------------------------------------------------------------
__global__ __launch_bounds__(256) void gru_combine(
    const float* __restrict__ gi, const float* __restrict__ gh,
    const float* __restrict__ b_ih, const float* __restrict__ b_hh,
    const float* __restrict__ hidden, float* __restrict__ hout)
{
  const int idx = blockIdx.x * 256 + threadIdx.x;
  if (idx >= B_ * H_) return;
  const int b = idx / H_, h = idx - b * H_;
  float ir = b_ih[h], iz = b_ih[H_ + h], in = b_ih[2 * H_ + h];
  float hr = b_hh[h], hz = b_hh[H_ + h], hn = b_hh[2 * H_ + h];
#pragma unroll
  for (int zz = 0; zz < Z_GI; ++zz) {
    const float* g = gi + (size_t)zz * B_ * NP_3H + (size_t)b * NP_3H;
    ir += g[h]; iz += g[H_ + h]; in += g[2 * H_ + h];
  }
#pragma unroll
  for (int zz = 0; zz < Z_GH; ++zz) {
    const float* g = gh + (size_t)zz * B_ * NP_3H + (size_t)b * NP_3H;
    hr += g[h]; hz += g[H_ + h]; hn += g[2 * H_ + h];
  }
  const float r = sigmoidf_(ir + hr);
  const float zg = sigmoidf_(iz + hz);
  const float n = tanhf(in + r * hn);
  hout[idx] = (1.f - zg) * n + zg * hidden[idx];
}

// ---------------------------------------------------------------------------
// maxout: sum mo_in partials (Z_MO=12 slabs: jlh z0-3, jle z4-5, jwv z6-11)
// + 3 biases, pairwise max, cast bf16. Zeros K-pad cols [500,512).
// ---------------------------------------------------------------------------
__global__ __launch_bounds__(256) void maxpair_cast(
    const float* __restrict__ mo_in,
    const float* __restrict__ b_lh, const float* __restrict__ b_le,
    const float* __restrict__ b_wv, unsigned short* __restrict__ mo_bf)
{
  const int idx = blockIdx.x * 256 + threadIdx.x;
  if (idx >= B_ * KP_PRED) return;
  const int r = idx >> 9, c = idx & 511;
  unsigned short o = 0;
  if (c < M_) {
    const int j0 = 2 * c, j1 = 2 * c + 1;
    float v0 = b_lh[j0] + b_le[j0] + b_wv[j0];
    float v1 = b_lh[j1] + b_le[j1] + b_wv[j1];
#pragma unroll
    for (int zz = 0; zz < Z_MO; ++zz) {
      const float* g = mo_in + (size_t)zz * B_ * NP_A + (size_t)r * NP_A;
      v0 += g[j0]; v1 += g[j1];
    }
    o = f2b(fmaxf(v0, v1));
  }
  mo_bf[idx] = o;
}

// ---------------------------------------------------------------------------
extern "C" void kernel_launch(void* const* d_in, const int* in_sizes, int n_in,
                              void* d_out, int out_size, void* d_ws, size_t ws_size,
                              hipStream_t stream)
{
  const int*   x       = (const int*)  d_in[0];
  const float* hidden  = (const float*)d_in[1];
  const float* outputs = (const float*)d_in[2];
  const float* emb     = (const float*)d_in[3];
  const float* W_hp    = (const float*)d_in[4];
  const float* b_hp    = (const float*)d_in[5];
  const float* W_op    = (const float*)d_in[6];
  const float* b_op    = (const float*)d_in[7];
  const float* v_e     = (const float*)d_in[8];
  const float* W_ih    = (const float*)d_in[9];
  const float* W_hh    = (const float*)d_in[10];
  const float* b_ih    = (const float*)d_in[11];
  const float* b_hh    = (const float*)d_in[12];
  const float* W_wv    = (const float*)d_in[13];
  const float* b_wv    = (const float*)d_in[14];
  const float* W_lh    = (const float*)d_in[15];
  const float* b_lh    = (const float*)d_in[16];
  const float* W_le    = (const float*)d_in[17];
  const float* b_le    = (const float*)d_in[18];
  const float* W_pred  = (const float*)d_in[19];
  const float* b_pred  = (const float*)d_in[20];

  char* w = (char*)d_ws;
  auto alloc = [&](size_t bytes) {
    char* p = w; w += (bytes + 255) & ~(size_t)255; return p;
  };
  unsigned short* outputs_bf = (unsigned short*)alloc((size_t)OROWS * KP_OUT * 2);
  unsigned short* W_op_bf    = (unsigned short*)alloc((size_t)NP_A * KP_OUT * 2);
  unsigned short* hidden_bf  = (unsigned short*)alloc((size_t)B_ * KP_HP * 2);
  unsigned short* cat3_bf    = (unsigned short*)alloc((size_t)B_ * LD_CAT * 2);
  unsigned short* mo_bf      = (unsigned short*)alloc((size_t)B_ * KP_PRED * 2);
  float* hp     = (float*)alloc((size_t)Z_HP * B_ * NP_A * 4);
  float* hpc    = (float*)alloc((size_t)B_ * NP_A * 4);
  float* energy = (float*)alloc((size_t)B_ * S_ * 4);
  float* gh     = (float*)alloc((size_t)Z_GH * B_ * NP_3H * 4);
  // union: opart (bf16, dead after energy_reduce) overlaps gi/mo_in
  // opart = 33.5MB; gi (12 x 1.5MB = 18.9MB) + mo_in (12 x 0.5MB = 6.3MB) fits
  char* un = w;
  unsigned short* opart = (unsigned short*)un;
  float* gi     = (float*)un;
  float* mo_in  = gi + (size_t)Z_GI * B_ * NP_3H;

  float* pred = (float*)d_out;
  float* hout = pred + (size_t)B_ * V_;

  const dim3 blk(256);
  const int FAR = 0x7fffffff;
  const SJob dummy = { nullptr, 0, nullptr, 0, 0, 0, nullptr, 0,
                       nullptr, 0, 1, 1, 1, FAR };

  // ---- merged casts: outputs / W_op / hidden (2912 blocks, unroll-4) ----
  {
    CJob jo  = { outputs, outputs_bf, OROWS * 256, 256, 2000, OROWS,
                 KP_OUT, 0, KP_OUT, 0,    2560 };
    CJob jwo = { W_op,    W_op_bf,    NP_A * 256,  256, 2000, A_,
                 KP_OUT, 0, KP_OUT, 2560, 320 };
    CJob jh  = { hidden,  hidden_bf,  B_ * 128,    128, 1000, B_,
                 KP_HP,  0, KP_HP,  2880, 32 };
    megacast<<<dim3(2912), blk, 0, stream>>>(jo, jwo, jh);
  }

  // ---- L1 skinny: hp (32t x Z8 = 256) + gh (94t x Z8 = 752) = 1008 blocks --
  {
    SJob jhp = { hidden_bf, KP_HP, W_hp, H_, A_, H_, hp, NP_A,
                 nullptr, 0, 16, Z_HP, 32, 0 };
    SJob jgh = { hidden_bf, KP_HP, W_hh, H_, 3 * H_, H_, gh, NP_3H,
                 nullptr, 0, 16, Z_GH, 94, 256 };
    gemm_skinny<<<dim3(1008), blk, 0, stream>>>(jhp, jgh, dummy, dummy);
  }
  hp_combine<<<dim3(B_ * NP_A / 256), blk, 0, stream>>>(hp, b_op, b_hp, hpc);

  // ---- o_proj partials: split-K=2, 1024 blocks, bf16 output ----
  gemm128_part<<<dim3(64, 8, Z_OP), blk, 0, stream>>>(
      outputs_bf, KP_OUT, W_op_bf, KP_OUT, opart, NP_A, KP_OUT / 64);

  // ---- energy ----
  energy_reduce<<<dim3(OROWS), blk, 0, stream>>>(opart, hpc, v_e, energy);

  // ---- softmax + ctx + cat3 ----
  softmax_ctx_cat<<<dim3(B_, 4), blk, 0, stream>>>(
      energy, outputs_bf, hidden, emb, x, cat3_bf);

  // ---- L2 skinny: gi (94t x Z12 = 1128) + mo_lh (32t x Z4 = 128, slabs 0-3)
  //      + mo_le (32t x Z2 = 64, slabs 4-5) + mo_wv (32t x Z6 = 192,
  //      slabs 6-11) = 1512 blocks ----
  {
    SJob jgi = { cat3_bf + 1000, LD_CAT, W_ih, 2620, 3 * H_, 2620, gi, NP_3H,
                 nullptr, 0, 41, Z_GI, 94, 0 };
    SJob jlh = { cat3_bf, LD_CAT, W_lh, H_, A_, H_,
                 mo_in, NP_A, nullptr, 0, 16, 4, 32, 1128 };
    SJob jle = { cat3_bf + 1000, LD_CAT, W_le, E_, A_, E_,
                 mo_in + (size_t)4 * B_ * NP_A, NP_A, nullptr, 0, 10, 2, 32, 1256 };
    SJob jwv = { cat3_bf + 1620, LD_CAT, W_wv, 2 * H_, A_, 2 * H_,
                 mo_in + (size_t)6 * B_ * NP_A, NP_A, nullptr, 0, 32, 6, 32, 1320 };
    gemm_skinny<<<dim3(1512), blk, 0, stream>>>(jgi, jlh, jle, jwv);
  }

  // ---- h_new ----
  gru_combine<<<dim3((B_ * H_ + 255) / 256), blk, 0, stream>>>(
      gi, gh, b_ih, b_hh, hidden, hout);

  // ---- mo (maxout + biases, 12 slabs) -> bf16 ----
  maxpair_cast<<<dim3((B_ * KP_PRED + 255) / 256), blk, 0, stream>>>(
      mo_in, b_lh, b_le, b_wv, mo_bf);

  // ---- prediction: counted-vmcnt pipelined, 469 blocks ----
  pred_gemm<<<dim3(469), blk, 0, stream>>>(mo_bf, W_pred, b_pred, pred);
}

// Round 19
// 160.736 us; speedup vs baseline: 1.0358x; 1.0358x over previous
//
#include <hip/hip_runtime.h>
#include <hip/hip_bf16.h>
#include <math.h>

typedef short bf16x8 __attribute__((ext_vector_type(8)));
typedef float f32x4 __attribute__((ext_vector_type(4)));
typedef unsigned short us8 __attribute__((ext_vector_type(8)));
typedef unsigned short us4 __attribute__((ext_vector_type(4)));

namespace {
constexpr int B_ = 128;
constexpr int S_ = 64;
constexpr int H_ = 1000;
constexpr int A_ = 1000;
constexpr int M_ = 500;
constexpr int V_ = 30000;
constexpr int E_ = 620;

constexpr int KP_OUT  = 2048;
constexpr int KP_HP   = 1024;
constexpr int KP_PRED = 512;
constexpr int LD_CAT  = 3712;  // [hidden 1000 | emb 620 | ctx 2000 | pad]
constexpr int NP_A    = 1024;
constexpr int NP_3H   = 3072;
constexpr int OROWS   = 8192;

constexpr int Z_HP = 4, Z_GI = 6, Z_GH = 4, Z_MO = 6, Z_OP = 2;

__device__ __forceinline__ unsigned short f2b(float f) {
  __hip_bfloat16 h = __float2bfloat16(f);
  return *reinterpret_cast<unsigned short*>(&h);
}
__device__ __forceinline__ float b2f(unsigned short u) {
  unsigned v = ((unsigned)u) << 16;
  return __uint_as_float(v);
}
__device__ __forceinline__ float sigmoidf_(float x) {
  return 1.0f / (1.0f + __expf(-x));
}
__device__ __forceinline__ void load_lds16(const void* g, void* l) {
  auto gp = reinterpret_cast<const __attribute__((address_space(1))) char*>(
      reinterpret_cast<uintptr_t>(g));
  unsigned loff = (unsigned)(uintptr_t)l;
  auto lp = reinterpret_cast<__attribute__((address_space(3))) char*>(loff);
  __builtin_amdgcn_global_load_lds(gp, lp, 16, 0, 0);
}
}  // namespace

// ---------------------------------------------------------------------------
// Merged cast (3 jobs: outputs, W_op, hidden). R8 unroll-2 structure.
// ---------------------------------------------------------------------------
struct CJob {
  const float* src; unsigned short* dst;
  int nchunks, cpr, Kel, Rs, ld, coff, Wlim, bstart, nblk;
};

__global__ __launch_bounds__(256) void megacast(CJob j0, CJob j1, CJob j2)
{
  const int bid = blockIdx.x;
  CJob j = j0;
  if (bid >= j1.bstart) j = j1;
  if (bid >= j2.bstart) j = j2;

  const int tpj = j.nblk << 8;
  const int base = ((bid - j.bstart) << 8) + (int)threadIdx.x;

  for (int i = base; i < j.nchunks; i += tpj * 2) {
    const int i2 = i + tpj;
    const bool okB = (i2 < j.nchunks);
    const int rA = i / j.cpr;
    const int cA = (i - rA * j.cpr) << 3;
    const int rB = okB ? (i2 / j.cpr) : 0;
    const int cB = okB ? ((i2 - rB * j.cpr) << 3) : 0;
    const bool fA = (rA < j.Rs) && (cA + 8 <= j.Kel);
    const bool fB = okB && (rB < j.Rs) && (cB + 8 <= j.Kel);

    float4 a0, a1, b0, b1;
    if (fA) {
      const float* s = j.src + (size_t)rA * j.Kel + cA;
      a0 = *(const float4*)s; a1 = *(const float4*)(s + 4);
    }
    if (fB) {
      const float* s = j.src + (size_t)rB * j.Kel + cB;
      b0 = *(const float4*)s; b1 = *(const float4*)(s + 4);
    }

    if (fA) {
      us8 o;
      o[0] = f2b(a0.x); o[1] = f2b(a0.y); o[2] = f2b(a0.z); o[3] = f2b(a0.w);
      o[4] = f2b(a1.x); o[5] = f2b(a1.y); o[6] = f2b(a1.z); o[7] = f2b(a1.w);
      *(us8*)(j.dst + (size_t)rA * j.ld + j.coff + cA) = o;
    } else {
      unsigned short* drow = j.dst + (size_t)rA * j.ld + j.coff;
#pragma unroll
      for (int e = 0; e < 8; ++e) {
        const int c = cA + e;
        if (c < j.Wlim) {
          const float v = (rA < j.Rs && c < j.Kel)
                              ? j.src[(size_t)rA * j.Kel + c] : 0.f;
          drow[c] = f2b(v);
        }
      }
    }
    if (okB) {
      if (fB) {
        us8 o;
        o[0] = f2b(b0.x); o[1] = f2b(b0.y); o[2] = f2b(b0.z); o[3] = f2b(b0.w);
        o[4] = f2b(b1.x); o[5] = f2b(b1.y); o[6] = f2b(b1.z); o[7] = f2b(b1.w);
        *(us8*)(j.dst + (size_t)rB * j.ld + j.coff + cB) = o;
      } else {
        unsigned short* drow = j.dst + (size_t)rB * j.ld + j.coff;
#pragma unroll
        for (int e = 0; e < 8; ++e) {
          const int c = cB + e;
          if (c < j.Wlim) {
            const float v = (rB < j.Rs && c < j.Kel)
                                ? j.src[(size_t)rB * j.Kel + c] : 0.f;
            drow[c] = f2b(v);
          }
        }
      }
    }
  }
}

// ---------------------------------------------------------------------------
// Skinny GEMM (R9 version), fp32-B direct, BK=64, double-buffered swizzled
// LDS, issue-early/write-late. Used for L1 (hp, gh) and L2 (gi, mo) jobs.
// ---------------------------------------------------------------------------
struct SJob {
  const unsigned short* A; int lda;
  const float* B; int ldb;
  int Nv, Kv;
  float* C; int ldc;
  const float* bias; int Ncol;
  int nK, Z, ntiles, bstart;
};

__global__ __launch_bounds__(256, 4) void gemm_skinny(
    SJob j0, SJob j1, SJob j2, SJob j3)
{
  __shared__ __align__(16) char Bs[2][4096];

  const int bid = blockIdx.x;
  SJob j = j0;
  if (bid >= j1.bstart) j = j1;
  if (bid >= j2.bstart) j = j2;
  if (bid >= j3.bstart) j = j3;
  const int lb = bid - j.bstart;
  const int tile = lb % j.ntiles, z = lb / j.ntiles;
  const int n0 = tile * 32;
  const int ks = (int)((long)j.nK * z / j.Z);
  const int ke = (int)((long)j.nK * (z + 1) / j.Z);

  const int t = threadIdx.x, lane = t & 63, wid = t >> 6;
  const int l15 = lane & 15, l4 = lane >> 4;
  const int mrow = (wid & 1) * 64;
  const int whalf = wid >> 1;

  const int srow = t >> 3;
  const int skq = (t & 7) * 8;
  const int grow = n0 + srow;
  const bool rowok = grow < j.Nv;
  const float* Bp = j.B + (size_t)(rowok ? grow : 0) * j.ldb;
  const unsigned swcol = (unsigned)(skq * 2) ^ (((unsigned)srow & 7u) << 4);

  const unsigned short* Arow = j.A + (size_t)(mrow + l15) * j.lda + l4 * 8;
  const int brow = whalf * 16 + l15;
  const unsigned bb = (unsigned)brow * 128;
  const unsigned bsw = (((unsigned)brow & 7u) << 4);

  float4 sf0, sf1;
  auto stage_load = [&](int kst) {
    const int gk = kst * 64 + skq;
    sf0 = make_float4(0.f, 0.f, 0.f, 0.f);
    sf1 = make_float4(0.f, 0.f, 0.f, 0.f);
    if (rowok) {
      if (gk + 8 <= j.Kv) {
        sf0 = *(const float4*)(Bp + gk);
        sf1 = *(const float4*)(Bp + gk + 4);
      } else {
        float tmp[8];
#pragma unroll
        for (int e = 0; e < 8; ++e)
          tmp[e] = (gk + e < j.Kv) ? Bp[gk + e] : 0.f;
        sf0 = make_float4(tmp[0], tmp[1], tmp[2], tmp[3]);
        sf1 = make_float4(tmp[4], tmp[5], tmp[6], tmp[7]);
      }
    }
  };
  auto stage_write = [&](int buf) {
    us8 o;
    o[0] = f2b(sf0.x); o[1] = f2b(sf0.y); o[2] = f2b(sf0.z); o[3] = f2b(sf0.w);
    o[4] = f2b(sf1.x); o[5] = f2b(sf1.y); o[6] = f2b(sf1.z); o[7] = f2b(sf1.w);
    *(us8*)((char*)Bs[buf] + srow * 128 + swcol) = o;
  };

  f32x4 acc[4] = {};
  stage_load(ks);
  stage_write(0);
  __syncthreads();

  for (int kst = ks; kst < ke; ++kst) {
    const int cur = (kst - ks) & 1;
    const bool more = (kst + 1 < ke);
    if (more) stage_load(kst + 1);
    bf16x8 Af[4][2];
#pragma unroll
    for (int kk = 0; kk < 2; ++kk)
#pragma unroll
      for (int mf = 0; mf < 4; ++mf)
        Af[mf][kk] = *(const bf16x8*)(Arow + (size_t)mf * 16 * j.lda +
                                      kst * 64 + kk * 32);
    bf16x8 Bf[2];
#pragma unroll
    for (int kk = 0; kk < 2; ++kk)
      Bf[kk] = *(const bf16x8*)((char*)Bs[cur] + bb +
                                ((unsigned)(kk * 64 + l4 * 16) ^ bsw));
#pragma unroll
    for (int kk = 0; kk < 2; ++kk)
#pragma unroll
      for (int mf = 0; mf < 4; ++mf)
        acc[mf] = __builtin_amdgcn_mfma_f32_16x16x32_bf16(Af[mf][kk], Bf[kk],
                                                          acc[mf], 0, 0, 0);
    if (more) stage_write(cur ^ 1);
    __syncthreads();
  }

  const int c = n0 + whalf * 16 + l15;
  if (j.bias) {
    if (c < j.Ncol) {
      const float bv = j.bias[c];
#pragma unroll
      for (int mf = 0; mf < 4; ++mf) {
        const int r = mrow + mf * 16 + l4 * 4;
#pragma unroll
        for (int q = 0; q < 4; ++q)
          j.C[(size_t)(r + q) * j.ldc + c] = acc[mf][q] + bv;
      }
    }
  } else {
    float* Cz = j.C + (size_t)z * 128 * j.ldc;
#pragma unroll
    for (int mf = 0; mf < 4; ++mf) {
      const int r = mrow + mf * 16 + l4 * 4;
#pragma unroll
      for (int q = 0; q < 4; ++q)
        Cz[(size_t)(r + q) * j.ldc + c] = acc[mf][q];
    }
  }
}

// ---------------------------------------------------------------------------
// pred GEMM v4 (T3/T4 counted-vmcnt pipeline) — R15 version.
// ---------------------------------------------------------------------------
__global__ __launch_bounds__(256, 2) void pred_gemm(
    const unsigned short* __restrict__ mo_bf,  // 128 x 512 bf16, K-pad zeroed
    const float* __restrict__ Wp,              // 30000 x 500 fp32
    const float* __restrict__ bias,
    float* __restrict__ C)                     // 128 x 30000
{
  __shared__ __align__(16) char Bs0[32768];  // 16 rows x 2048B fp32
  __shared__ __align__(16) char Bs1[32768];

  const int t = threadIdx.x, lane = t & 63, wid = t >> 6;
  const int l15 = lane & 15, l4 = lane >> 4;
  const int n0 = blockIdx.x * 64;
  const int mrow = wid * 32;

  // ---- A fragments -> VGPRs (issued before any staging: oldest VMEM) ----
  bf16x8 af[2][16];
#pragma unroll
  for (int ksl = 0; ksl < 16; ++ksl)
#pragma unroll
    for (int mf = 0; mf < 2; ++mf)
      af[mf][ksl] = *(const bf16x8*)(mo_bf +
          (size_t)(mrow + mf * 16 + l15) * KP_PRED + ksl * 32 + l4 * 8);

  auto stage = [&](int st, char* buf) {
#pragma unroll
    for (int i = 0; i < 8; ++i) {
      const unsigned off = (unsigned)i * 4096 + (unsigned)t * 16;
      const unsigned row = off >> 11, colb = off & 2047u;
      const unsigned sc = colb ^ ((row & 7u) << 4);  // pre-swizzled source
      const int rg = n0 + st * 16 + (int)row;
      const bool ok = (rg < V_) && (sc + 16 <= 2000u);
      const char* src = ok ? ((const char*)Wp + (size_t)rg * 2000 + sc)
                           : (const char*)Wp;
      load_lds16(src, buf + off);
    }
  };

  f32x4 acc[4][2] = {};

  stage(0, Bs0);
  stage(1, Bs1);

#define PWAIT(N) do {                                              \
    asm volatile("s_waitcnt vmcnt(" #N ")" ::: "memory");          \
    __builtin_amdgcn_sched_barrier(0);                             \
    __builtin_amdgcn_s_barrier();                                  \
  } while (0)

#define PCOMPUTE(T, BUF) do {                                              \
    const char* Brow_ = (const char*)(BUF) + (unsigned)l15 * 2048;         \
    const unsigned sw_ = ((unsigned)l15 & 7u) << 4;                        \
    _Pragma("unroll")                                                      \
    for (int ksl = 0; ksl < 16; ++ksl) {                                   \
      const unsigned base_ = (unsigned)(ksl * 128 + l4 * 32);              \
      const float4 f0_ = *(const float4*)(Brow_ + (base_ ^ sw_));          \
      const float4 f1_ = *(const float4*)(Brow_ + ((base_ + 16) ^ sw_));   \
      bf16x8 bf_;                                                          \
      bf_[0] = (short)f2b(f0_.x); bf_[1] = (short)f2b(f0_.y);              \
      bf_[2] = (short)f2b(f0_.z); bf_[3] = (short)f2b(f0_.w);              \
      bf_[4] = (short)f2b(f1_.x); bf_[5] = (short)f2b(f1_.y);              \
      bf_[6] = (short)f2b(f1_.z); bf_[7] = (short)f2b(f1_.w);              \
      acc[T][0] = __builtin_amdgcn_mfma_f32_16x16x32_bf16(af[0][ksl], bf_, \
                                                          acc[T][0], 0, 0, 0); \
      acc[T][1] = __builtin_amdgcn_mfma_f32_16x16x32_bf16(af[1][ksl], bf_, \
                                                          acc[T][1], 0, 0, 0); \
    }                                                                      \
  } while (0)

  PWAIT(8);   // s0 ready (A + s0 retired; s1 in flight)
  PCOMPUTE(0, Bs0);
  __builtin_amdgcn_s_barrier();   // all waves done reading Bs0
  stage(2, Bs0);

  PWAIT(8);   // s1 ready (s2 in flight)
  PCOMPUTE(1, Bs1);
  __builtin_amdgcn_s_barrier();   // all waves done reading Bs1
  stage(3, Bs1);

  PWAIT(8);   // s2 ready (s3 in flight)
  PCOMPUTE(2, Bs0);

  PWAIT(0);   // s3 ready
  PCOMPUTE(3, Bs1);

#undef PWAIT
#undef PCOMPUTE

#pragma unroll
  for (int st = 0; st < 4; ++st) {
    const int c = n0 + st * 16 + l15;
    if (c < V_) {
      const float bv = bias[c];
#pragma unroll
      for (int mf = 0; mf < 2; ++mf) {
        const int r = mrow + mf * 16 + l4 * 4;
#pragma unroll
        for (int q = 0; q < 4; ++q)
          C[(size_t)(r + q) * V_ + c] = acc[st][mf][q] + bv;
      }
    }
  }
}

// ---------------------------------------------------------------------------
// o_proj GEMM (R12/R15 version): 128x128 tile, BK=64, swizzled LDS,
// global_load_lds both sides, __syncthreads, 4 blocks/CU. bf16 partials.
// ---------------------------------------------------------------------------
__global__ __launch_bounds__(256, 4) void gemm128_part(
    const unsigned short* __restrict__ Abf, int ldA,
    const unsigned short* __restrict__ Bbf, int ldB,
    unsigned short* __restrict__ Cout, int ldc, int nK)
{
  __shared__ __align__(16) char As[16384];
  __shared__ __align__(16) char Bs[16384];

  const int t = threadIdx.x;
  const int lane = t & 63, wid = t >> 6;
  const int wm = wid >> 1, wn = wid & 1;
  const int l15 = lane & 15, l4 = lane >> 4;
  const int m0 = blockIdx.x * 128;
  const int n0 = blockIdx.y * 128;
  const int z = blockIdx.z, Z = gridDim.z;
  const int ks = (int)((long)nK * z / Z), ke = (int)((long)nK * (z + 1) / Z);

  f32x4 acc[4][4] = {};

  for (int kst = ks; kst < ke; ++kst) {
    const int k0 = kst * 64;
#pragma unroll
    for (int c = 0; c < 4; ++c) {
      const unsigned ou = c * 4096 + wid * 1024;
      const unsigned oo = ou + lane * 16;
      const unsigned row = oo >> 7, cb = oo & 127u;
      const unsigned scb = cb ^ ((row & 7u) << 4);
      load_lds16((const char*)Abf + ((size_t)(m0 + row) * ldA + k0) * 2 + scb,
                 As + ou);
    }
#pragma unroll
    for (int c = 0; c < 4; ++c) {
      const unsigned ou = c * 4096 + wid * 1024;
      const unsigned oo = ou + lane * 16;
      const unsigned row = oo >> 7, cb = oo & 127u;
      const unsigned scb = cb ^ ((row & 7u) << 4);
      load_lds16((const char*)Bbf + ((size_t)(n0 + row) * ldB + k0) * 2 + scb,
                 Bs + ou);
    }
    __syncthreads();

#pragma unroll
    for (int kk = 0; kk < 2; ++kk) {
      bf16x8 af[4], bfr[4];
#pragma unroll
      for (int i = 0; i < 4; ++i) {
        const unsigned ra = wm * 64 + i * 16 + l15;
        const unsigned ca = (unsigned)(kk * 64 + l4 * 16) ^ ((ra & 7u) << 4);
        af[i] = *(const bf16x8*)(As + ra * 128 + ca);
        const unsigned rb = wn * 64 + i * 16 + l15;
        const unsigned cb2 = (unsigned)(kk * 64 + l4 * 16) ^ ((rb & 7u) << 4);
        bfr[i] = *(const bf16x8*)(Bs + rb * 128 + cb2);
      }
#pragma unroll
      for (int i = 0; i < 4; ++i)
#pragma unroll
        for (int jj = 0; jj < 4; ++jj)
          acc[i][jj] = __builtin_amdgcn_mfma_f32_16x16x32_bf16(af[i], bfr[jj],
                                                               acc[i][jj], 0, 0, 0);
    }
    __syncthreads();
  }

  unsigned short* Cz = Cout + (size_t)z * OROWS * ldc;
#pragma unroll
  for (int i = 0; i < 4; ++i) {
    const int r = m0 + wm * 64 + i * 16 + l4 * 4;
#pragma unroll
    for (int jj = 0; jj < 4; ++jj) {
      const int c = n0 + wn * 64 + jj * 16 + l15;
#pragma unroll
      for (int q = 0; q < 4; ++q)
        Cz[(size_t)(r + q) * ldc + c] = f2b(acc[i][jj][q]);
    }
  }
}

// ---------------------------------------------------------------------------
// hpc[b][c] = b_op[c] + b_hp[c] + sum_z hp_partial[z][b][c]
// ---------------------------------------------------------------------------
__global__ __launch_bounds__(256) void hp_combine(
    const float* __restrict__ hp, const float* __restrict__ b_op,
    const float* __restrict__ b_hp, float* __restrict__ hpc)
{
  const int idx = blockIdx.x * 256 + threadIdx.x;
  if (idx >= B_ * NP_A) return;
  const int c = idx & (NP_A - 1);
  float s = (c < A_) ? (b_op[c] + b_hp[c]) : 0.f;
#pragma unroll
  for (int zz = 0; zz < Z_HP; ++zz) s += hp[(size_t)zz * B_ * NP_A + idx];
  hpc[idx] = s;
}

// ---------------------------------------------------------------------------
// energy[r] = sum_c tanh(op0[r,c] + op1[r,c] + hpc[b,c]) * ve[c]   (opart bf16)
// ---------------------------------------------------------------------------
__global__ __launch_bounds__(256) void energy_reduce(
    const unsigned short* __restrict__ opart, const float* __restrict__ hpc,
    const float* __restrict__ ve, float* __restrict__ energy)
{
  const int r = blockIdx.x;
  const int b = r >> 6;
  const int t = threadIdx.x;
  float s = 0.f;
  if (t < 250) {
    const int c0 = t * 4;
    const us4 v0 = *(const us4*)(opart + (size_t)r * NP_A + c0);
    const us4 v1 = *(const us4*)(opart + (size_t)OROWS * NP_A + (size_t)r * NP_A + c0);
    const float4 h = *(const float4*)(hpc + (size_t)b * NP_A + c0);
    const float4 vv = *(const float4*)(ve + c0);
    s = tanhf(b2f(v0[0]) + b2f(v1[0]) + h.x) * vv.x
      + tanhf(b2f(v0[1]) + b2f(v1[1]) + h.y) * vv.y
      + tanhf(b2f(v0[2]) + b2f(v1[2]) + h.z) * vv.z
      + tanhf(b2f(v0[3]) + b2f(v1[3]) + h.w) * vv.w;
  }
#pragma unroll
  for (int w = 1; w < 64; w <<= 1) s += __shfl_xor(s, w);
  __shared__ float red[4];
  if ((t & 63) == 0) red[t >> 6] = s;
  __syncthreads();
  if (t == 0) energy[r] = red[0] + red[1] + red[2] + red[3];
}

// ---------------------------------------------------------------------------
// softmax + ctx (from outputs_bf) + cat3 build.  grid (B, 4)
// ---------------------------------------------------------------------------
__global__ __launch_bounds__(256) void softmax_ctx_cat(
    const float* __restrict__ energy, const unsigned short* __restrict__ outb,
    const float* __restrict__ hidden, const float* __restrict__ emb,
    const int* __restrict__ x, unsigned short* __restrict__ cat3)
{
  const int b = blockIdx.x, yq = blockIdx.y;
  const int t = threadIdx.x;
  __shared__ float attn[S_];
  __shared__ float sinv_s;

  if (t < 64) {
    const float e = energy[b * S_ + t];
    float m = e;
#pragma unroll
    for (int w = 1; w < 64; w <<= 1) m = fmaxf(m, __shfl_xor(m, w));
    const float p = __expf(e - m);
    float s = p;
#pragma unroll
    for (int w = 1; w < 64; w <<= 1) s += __shfl_xor(s, w);
    attn[t] = p;
    if (t == 0) sinv_s = 1.f / s;
  }
  __syncthreads();
  const float inv = sinv_s;
  unsigned short* catb = cat3 + (size_t)b * LD_CAT;

  // ctx -> cols 1620..3619
  {
    const int c0 = (250 * yq) / 4, c1 = (250 * (yq + 1)) / 4;
    const unsigned short* ob = outb + (size_t)b * S_ * KP_OUT;
    for (int kk = c0 + t; kk < c1; kk += 256) {
      float a[8] = {0.f, 0.f, 0.f, 0.f, 0.f, 0.f, 0.f, 0.f};
      for (int s = 0; s < S_; ++s) {
        const float w = attn[s];
        const us8 v = *(const us8*)(ob + (size_t)s * KP_OUT + kk * 8);
#pragma unroll
        for (int jj = 0; jj < 8; ++jj) a[jj] = fmaf(w, b2f(v[jj]), a[jj]);
      }
      us4 lo, hi;
#pragma unroll
      for (int jj = 0; jj < 4; ++jj) {
        lo[jj] = f2b(a[jj] * inv); hi[jj] = f2b(a[jj + 4] * inv);
      }
      *(us4*)(catb + 1620 + kk * 8) = lo;
      *(us4*)(catb + 1620 + kk * 8 + 4) = hi;
    }
  }
  // hidden -> cols 0..999
  {
    const int c0 = (250 * yq) / 4, c1 = (250 * (yq + 1)) / 4;
    for (int kk = c0 + t; kk < c1; kk += 256) {
      const float4 f = *(const float4*)(hidden + (size_t)b * H_ + kk * 4);
      us4 v; v[0] = f2b(f.x); v[1] = f2b(f.y); v[2] = f2b(f.z); v[3] = f2b(f.w);
      *(us4*)(catb + kk * 4) = v;
    }
  }
  // emb_x -> cols 1000..1619
  {
    const int xi = x[b];
    const int c0 = (155 * yq) / 4, c1 = (155 * (yq + 1)) / 4;
    for (int kk = c0 + t; kk < c1; kk += 256) {
      const float4 f = *(const float4*)(emb + (size_t)xi * E_ + kk * 4);
      us4 v; v[0] = f2b(f.x); v[1] = f2b(f.y); v[2] = f2b(f.z); v[3] = f2b(f.w);
      *(us4*)(catb + 1000 + kk * 4) = v;
    }
  }
  // zero pad cols 3620..3711
  if (yq == 3) {
    for (int kk = t; kk < 23; kk += 256) {
      us4 v; v[0] = 0; v[1] = 0; v[2] = 0; v[3] = 0;
      *(us4*)(catb + 3620 + kk * 4) = v;
    }
  }
}

// ---------------------------------------------------------------------------
// GRU combine: sums gi partials (Z_GI) + gh partials (Z_GH) + biases
// ---------------------------------------------------------------------------
__global__ __launch_bounds__(256) void gru_combine(
    const float* __restrict__ gi, const float* __restrict__ gh,
    const float* __restrict__ b_ih, const float* __restrict__ b_hh,
    const float* __restrict__ hidden, float* __restrict__ hout)
{
  const int idx = blockIdx.x * 256 + threadIdx.x;
  if (idx >= B_ * H_) return;
  const int b = idx / H_, h = idx - b * H_;
  float ir = b_ih[h], iz = b_ih[H_ + h], in = b_ih[2 * H_ + h];
  float hr = b_hh[h], hz = b_hh[H_ + h], hn = b_hh[2 * H_ + h];
#pragma unroll
  for (int zz = 0; zz < Z_GI; ++zz) {
    const float* g = gi + (size_t)zz * B_ * NP_3H + (size_t)b * NP_3H;
    ir += g[h]; iz += g[H_ + h]; in += g[2 * H_ + h];
  }
#pragma unroll
  for (int zz = 0; zz < Z_GH; ++zz) {
    const float* g = gh + (size_t)zz * B_ * NP_3H + (size_t)b * NP_3H;
    hr += g[h]; hz += g[H_ + h]; hn += g[2 * H_ + h];
  }
  const float r = sigmoidf_(ir + hr);
  const float zg = sigmoidf_(iz + hz);
  const float n = tanhf(in + r * hn);
  hout[idx] = (1.f - zg) * n + zg * hidden[idx];
}

// ---------------------------------------------------------------------------
// maxout: sum mo_in partials (Z_MO=6 slabs: jlh z0-1, jle z2, jwv z3-5)
// + 3 biases, pairwise max, cast bf16. Zeros K-pad cols [500,512) — pred_gemm
// relies on this.
// ---------------------------------------------------------------------------
__global__ __launch_bounds__(256) void maxpair_cast(
    const float* __restrict__ mo_in,
    const float* __restrict__ b_lh, const float* __restrict__ b_le,
    const float* __restrict__ b_wv, unsigned short* __restrict__ mo_bf)
{
  const int idx = blockIdx.x * 256 + threadIdx.x;
  if (idx >= B_ * KP_PRED) return;
  const int r = idx >> 9, c = idx & 511;
  unsigned short o = 0;
  if (c < M_) {
    const int j0 = 2 * c, j1 = 2 * c + 1;
    float v0 = b_lh[j0] + b_le[j0] + b_wv[j0];
    float v1 = b_lh[j1] + b_le[j1] + b_wv[j1];
#pragma unroll
    for (int zz = 0; zz < Z_MO; ++zz) {
      const float* g = mo_in + (size_t)zz * B_ * NP_A + (size_t)r * NP_A;
      v0 += g[j0]; v1 += g[j1];
    }
    o = f2b(fmaxf(v0, v1));
  }
  mo_bf[idx] = o;
}

// ---------------------------------------------------------------------------
extern "C" void kernel_launch(void* const* d_in, const int* in_sizes, int n_in,
                              void* d_out, int out_size, void* d_ws, size_t ws_size,
                              hipStream_t stream)
{
  const int*   x       = (const int*)  d_in[0];
  const float* hidden  = (const float*)d_in[1];
  const float* outputs = (const float*)d_in[2];
  const float* emb     = (const float*)d_in[3];
  const float* W_hp    = (const float*)d_in[4];
  const float* b_hp    = (const float*)d_in[5];
  const float* W_op    = (const float*)d_in[6];
  const float* b_op    = (const float*)d_in[7];
  const float* v_e     = (const float*)d_in[8];
  const float* W_ih    = (const float*)d_in[9];
  const float* W_hh    = (const float*)d_in[10];
  const float* b_ih    = (const float*)d_in[11];
  const float* b_hh    = (const float*)d_in[12];
  const float* W_wv    = (const float*)d_in[13];
  const float* b_wv    = (const float*)d_in[14];
  const float* W_lh    = (const float*)d_in[15];
  const float* b_lh    = (const float*)d_in[16];
  const float* W_le    = (const float*)d_in[17];
  const float* b_le    = (const float*)d_in[18];
  const float* W_pred  = (const float*)d_in[19];
  const float* b_pred  = (const float*)d_in[20];

  char* w = (char*)d_ws;
  auto alloc = [&](size_t bytes) {
    char* p = w; w += (bytes + 255) & ~(size_t)255; return p;
  };
  unsigned short* outputs_bf = (unsigned short*)alloc((size_t)OROWS * KP_OUT * 2);
  unsigned short* W_op_bf    = (unsigned short*)alloc((size_t)NP_A * KP_OUT * 2);
  unsigned short* hidden_bf  = (unsigned short*)alloc((size_t)B_ * KP_HP * 2);
  unsigned short* cat3_bf    = (unsigned short*)alloc((size_t)B_ * LD_CAT * 2);
  unsigned short* mo_bf      = (unsigned short*)alloc((size_t)B_ * KP_PRED * 2);
  float* hp     = (float*)alloc((size_t)Z_HP * B_ * NP_A * 4);
  float* hpc    = (float*)alloc((size_t)B_ * NP_A * 4);
  float* energy = (float*)alloc((size_t)B_ * S_ * 4);
  float* gh     = (float*)alloc((size_t)Z_GH * B_ * NP_3H * 4);
  // union: opart (bf16, dead after energy_reduce) overlaps gi/mo_in
  char* un = w;
  unsigned short* opart = (unsigned short*)un;      // Z_OP*OROWS*NP_A us = 33.5MB
  float* gi     = (float*)un;                       // Z_GI*B_*NP_3H f
  float* mo_in  = gi + (size_t)Z_GI * B_ * NP_3H;   // Z_MO slabs of B_*NP_A f

  float* pred = (float*)d_out;
  float* hout = pred + (size_t)B_ * V_;

  const dim3 blk(256);
  const int FAR = 0x7fffffff;
  const SJob dummy = { nullptr, 0, nullptr, 0, 0, 0, nullptr, 0,
                       nullptr, 0, 1, 1, 1, FAR };

  // ---- merged casts: outputs / W_op / hidden (2912 blocks) ----
  {
    CJob jo  = { outputs, outputs_bf, OROWS * 256, 256, 2000, OROWS,
                 KP_OUT, 0, KP_OUT, 0,    2560 };
    CJob jwo = { W_op,    W_op_bf,    NP_A * 256,  256, 2000, A_,
                 KP_OUT, 0, KP_OUT, 2560, 320 };
    CJob jh  = { hidden,  hidden_bf,  B_ * 128,    128, 1000, B_,
                 KP_HP,  0, KP_HP,  2880, 32 };
    megacast<<<dim3(2912), blk, 0, stream>>>(jo, jwo, jh);
  }

  // ---- L1 skinny: hp (32t x Z4 = 128) + gh (94t x Z4 = 376) = 504 blocks ---
  {
    SJob jhp = { hidden_bf, KP_HP, W_hp, H_, A_, H_, hp, NP_A,
                 nullptr, 0, 16, Z_HP, 32, 0 };
    SJob jgh = { hidden_bf, KP_HP, W_hh, H_, 3 * H_, H_, gh, NP_3H,
                 nullptr, 0, 16, Z_GH, 94, 128 };
    gemm_skinny<<<dim3(504), blk, 0, stream>>>(jhp, jgh, dummy, dummy);
  }
  hp_combine<<<dim3(B_ * NP_A / 256), blk, 0, stream>>>(hp, b_op, b_hp, hpc);

  // ---- o_proj partials: split-K=2, 1024 blocks, bf16 output ----
  gemm128_part<<<dim3(64, 8, Z_OP), blk, 0, stream>>>(
      outputs_bf, KP_OUT, W_op_bf, KP_OUT, opart, NP_A, KP_OUT / 64);

  // ---- energy ----
  energy_reduce<<<dim3(OROWS), blk, 0, stream>>>(opart, hpc, v_e, energy);

  // ---- softmax + ctx + cat3 ----
  softmax_ctx_cat<<<dim3(B_, 4), blk, 0, stream>>>(
      energy, outputs_bf, hidden, emb, x, cat3_bf);

  // ---- L2 skinny: gi (94t x Z6 = 564) + mo_lh (Z2: slabs 0-1) +
  //      mo_le (Z1: slab 2) + mo_wv (Z3: slabs 3-5) = 756 blocks ----
  {
    SJob jgi = { cat3_bf + 1000, LD_CAT, W_ih, 2620, 3 * H_, 2620, gi, NP_3H,
                 nullptr, 0, 41, Z_GI, 94, 0 };
    SJob jlh = { cat3_bf, LD_CAT, W_lh, H_, A_, H_,
                 mo_in, NP_A, nullptr, 0, 16, 2, 32, 564 };
    SJob jle = { cat3_bf + 1000, LD_CAT, W_le, E_, A_, E_,
                 mo_in + (size_t)2 * B_ * NP_A, NP_A, nullptr, 0, 10, 1, 32, 628 };
    SJob jwv = { cat3_bf + 1620, LD_CAT, W_wv, 2 * H_, A_, 2 * H_,
                 mo_in + (size_t)3 * B_ * NP_A, NP_A, nullptr, 0, 32, 3, 32, 660 };
    gemm_skinny<<<dim3(756), blk, 0, stream>>>(jgi, jlh, jle, jwv);
  }

  // ---- h_new ----
  gru_combine<<<dim3((B_ * H_ + 255) / 256), blk, 0, stream>>>(
      gi, gh, b_ih, b_hh, hidden, hout);

  // ---- mo (maxout + biases, 6 slabs) -> bf16 ----
  maxpair_cast<<<dim3((B_ * KP_PRED + 255) / 256), blk, 0, stream>>>(
      mo_in, b_lh, b_le, b_wv, mo_bf);

  // ---- prediction: counted-vmcnt pipelined, 469 blocks ----
  pred_gemm<<<dim3(469), blk, 0, stream>>>(mo_bf, W_pred, b_pred, pred);
}